// Round 1
// baseline (38.121 us; speedup 1.0000x reference)
//
#include <hip/hip_runtime.h>

// SNE (surface normal estimation) — 3x3 stencil over 1080x1920 f32 depth.
// Round 1: exact-mirror semantics, early-out for the NaN-poisoned region.
//
// Key semantic notes (vs jax reference):
//  - conv is full 9-tap MAC: 0-weight taps see D=inf (rows v<=cy) -> 0*inf=NaN
//    -> Gx,Gy NaN for any pixel whose window touches a Z=0 row -> output is
//    deterministically (0,0,-1). Early-out: (i-1) <= cy (depth>0 guaranteed).
//  - all arithmetic mirrored in f32 IEEE order, fp contract OFF (XLA CPU emits
//    separate fmul/fadd), precise atanf/sinf/cosf/sqrtf/divides.

#define HH 1080
#define WW 1920
#define HWSZ (HH * WW)

__global__ __launch_bounds__(256)
void sne_kernel(const float* __restrict__ depth, const float* __restrict__ cam,
                float* __restrict__ out)
{
#pragma clang fp contract(off)
    const int j = blockIdx.x * 256 + threadIdx.x;
    const int i = blockIdx.y;
    if (j >= WW) return;
    const int idx = i * WW + j;

    const float fx = cam[0];
    const float cx = cam[2];
    const float fy = cam[4];
    const float cy = cam[5];

    // Early-out: if any in-window row r (r >= i-1) has r <= cy, then Y<=0 ->
    // Z=0 -> D=inf -> 0*inf NaN in the GXY conv -> phi NaN -> sums all 0 ->
    // theta NaN -> bad branch -> (0,0,-1), sign=+1. Unconditional.
    if ((float)(i - 1) <= cy) {
        out[idx]            = 0.0f;
        out[HWSZ + idx]     = 0.0f;
        out[2 * HWSZ + idx] = -1.0f;
        return;
    }

    // Hot path: every in-bounds window row r > cy -> Y>0 -> Z=depth (>0), no selects.
    const int  jm = j - 1, jp = j + 1;
    const bool okW = (jm >= 0);
    const bool okE = (jp < WW);
    const bool okS = (i + 1 < HH);

    const float* rowN = depth + (size_t)(i - 1) * WW;
    const float* rowC = depth + (size_t)i * WW;
    const float* rowS = depth + (size_t)(i + 1) * WW;

    float z[3][3];
    z[0][0] = okW ? rowN[jm] : 0.0f;  z[0][1] = rowN[j];  z[0][2] = okE ? rowN[jp] : 0.0f;
    z[1][0] = okW ? rowC[jm] : 0.0f;  z[1][1] = rowC[j];  z[1][2] = okE ? rowC[jp] : 0.0f;
    if (okS) {
        z[2][0] = okW ? rowS[jm] : 0.0f;  z[2][1] = rowS[j];  z[2][2] = okE ? rowS[jp] : 0.0f;
    } else {
        z[2][0] = 0.0f;  z[2][1] = 0.0f;  z[2][2] = 0.0f;
    }

    // Per-position X, Y in exact reference order: (z * (coord - c)) / fx.
    float vr[3], uc[3];
    vr[0] = (float)(i - 1) - cy;  vr[1] = (float)i - cy;  vr[2] = (float)(i + 1) - cy;
    uc[0] = (float)jm - cx;       uc[1] = (float)j - cx;  uc[2] = (float)jp - cx;

    float X[3][3], Y[3][3];
    #pragma unroll
    for (int di = 0; di < 3; ++di) {
        #pragma unroll
        for (int dj = 0; dj < 3; ++dj) {
            const float zz = z[di][dj];
            Y[di][dj] = (zz * vr[di]) / fx;
            X[di][dj] = (zz * uc[dj]) / fx;   // reference divides X by fx too
        }
    }
    // Zero-padding must contribute exactly +0 (not -0) like the conv pad.
    if (!okW) { X[0][0] = 0.0f; X[1][0] = 0.0f; X[2][0] = 0.0f; }
    if (!okE) { X[0][2] = 0.0f; X[1][2] = 0.0f; X[2][2] = 0.0f; }
    if (!okS) { X[2][0] = 0.0f; X[2][1] = 0.0f; X[2][2] = 0.0f; }

    // D at the 4 cross neighbors (pad -> 0 contribution).
    const float dW = okW ? 1.0f / z[1][0] : 0.0f;
    const float dE = okE ? 1.0f / z[1][2] : 0.0f;
    const float dN = 1.0f / z[0][1];
    const float dS = okS ? 1.0f / z[2][1] : 0.0f;

    const float gx = dE - dW;             // (-1)*W + (+1)*E accumulation order
    const float gy = dS - dN;

    const float nx_t = gx * fx;
    const float ny_t = gy * fy;

    const float phi = atanf(ny_t / nx_t) + 3.141592657f;
    const float a = cosf(phi);
    const float b = sinf(phi);

    const float h2 = nx_t * nx_t + ny_t * ny_t;   // matches (nx^2 + ny^2) + nz^2 assoc
    const float Xc = X[1][1], Yc = Y[1][1], Zc = z[1][1];

    float sum_nx = 0.0f, sum_ny = 0.0f, sum_nz = 0.0f;

    const int off_di[8] = {0, 0, 0, 1, 1, 2, 2, 2};
    const int off_dj[8] = {0, 1, 2, 0, 2, 0, 1, 2};
    #pragma unroll
    for (int k = 0; k < 8; ++k) {
        const int di = off_di[k], dj = off_dj[k];
        const float Xd = Xc - X[di][dj];
        const float Yd = Yc - Y[di][dj];
        const float Zd = Zc - z[di][dj];
        const float w   = nx_t * Xd + ny_t * Yd;
        const float nzi = w / Zd;                       // 0/0 -> NaN, x/0 -> inf
        const float nrm = sqrtf(h2 + nzi * nzi);
        const float nxi = nx_t / nrm;
        const float nyi = ny_t / nrm;
        const float nzn = nzi / nrm;                    // inf/inf -> NaN
        sum_nx += (nxi != nxi) ? 0.0f : nxi;
        sum_ny += (nyi != nyi) ? 0.0f : nyi;
        sum_nz += (nzn != nzn) ? 0.0f : nzn;
    }

    const float g     = (sum_nx * a + sum_ny * b) / sum_nz;
    const float theta = -atanf(g);
    const float st    = sinf(theta);
    float nxo = st * a;
    float nyo = st * b;
    float nzo = cosf(theta);
    if (nzo != nzo) { nxo = 0.0f; nyo = 0.0f; nzo = -1.0f; }
    const float sgn = (nyo > 0.0f) ? -1.0f : 1.0f;

    out[idx]            = nxo * sgn;
    out[HWSZ + idx]     = nyo * sgn;
    out[2 * HWSZ + idx] = nzo * sgn;
}

extern "C" void kernel_launch(void* const* d_in, const int* in_sizes, int n_in,
                              void* d_out, int out_size, void* d_ws, size_t ws_size,
                              hipStream_t stream) {
    const float* depth = (const float*)d_in[0];
    const float* cam   = (const float*)d_in[1];
    float* out = (float*)d_out;
    dim3 grid((WW + 255) / 256, HH);
    sne_kernel<<<grid, dim3(256, 1, 1), 0, stream>>>(depth, cam, out);
}

// Round 2
// 28.794 us; speedup vs baseline: 1.3239x; 1.3239x over previous
//
#include <hip/hip_runtime.h>

// SNE — 3x3 stencil surface normals, 1080x1920 f32.
// Round 2: transcendental elimination via exact trig identities (including the
// reference's inexact-PI phase offset as an exact rotation constant) and
// divide reduction where no downstream cancellation amplifies the ulps.
//
// Semantics notes:
//  - rows with (i-1) <= cy: D=inf rows inside the GXY conv window -> 0*inf=NaN
//    -> deterministic (0,0,-1) output. Early-out.
//  - cos(atan(r)+PI_f): PI_f = float(3.141592657) = pi + 8.742278e-8, so
//    a = -c + S2*s, b = -s - S2*c with S2 = 8.7422780e-8 (cos(PI_f) = -1.0f
//    exactly in f32). c = |nx|/hyp, s = ny*copysign(1,nx)/hyp handles the
//    atan (not atan2!) quadrant and r = +-inf exactly.
//  - sum_nx = nx_t * sum_k(1/nrm_k): all terms share sign(nx_t) -> no
//    cancellation -> safe to factor. sum_nz keeps per-k IEEE divides (it is
//    the sign-sensitive cancellation sum feeding g).
//  - g = +-inf guard mirrors sinf/cosf(-+1.5707964f) = -+1.0f / -4.3711388e-8f.

#define HH 1080
#define WW 1920
#define HWSZ (HH * WW)

__global__ __launch_bounds__(256)
void sne_kernel(const float* __restrict__ depth, const float* __restrict__ cam,
                float* __restrict__ out)
{
#pragma clang fp contract(off)
    const int j = blockIdx.x * 256 + threadIdx.x;
    const int i = blockIdx.y;
    if (j >= WW) return;
    const int idx = i * WW + j;

    const float fx = cam[0];
    const float cx = cam[2];
    const float fy = cam[4];
    const float cy = cam[5];

    if ((float)(i - 1) <= cy) {
        out[idx]            = 0.0f;
        out[HWSZ + idx]     = 0.0f;
        out[2 * HWSZ + idx] = -1.0f;
        return;
    }

    const int  jm = j - 1, jp = j + 1;
    const bool okW = (jm >= 0);
    const bool okE = (jp < WW);
    const bool okS = (i + 1 < HH);

    const float* rowN = depth + (size_t)(i - 1) * WW;
    const float* rowC = depth + (size_t)i * WW;
    const float* rowS = depth + (size_t)(i + 1) * WW;

    float z[3][3];
    z[0][0] = okW ? rowN[jm] : 0.0f;  z[0][1] = rowN[j];  z[0][2] = okE ? rowN[jp] : 0.0f;
    z[1][0] = okW ? rowC[jm] : 0.0f;  z[1][1] = rowC[j];  z[1][2] = okE ? rowC[jp] : 0.0f;
    if (okS) {
        z[2][0] = okW ? rowS[jm] : 0.0f;  z[2][1] = rowS[j];  z[2][2] = okE ? rowS[jp] : 0.0f;
    } else {
        z[2][0] = 0.0f;  z[2][1] = 0.0f;  z[2][2] = 0.0f;
    }

    const float rfx = 1.0f / fx;   // uniform; X,Y scale (no cancellation right after)

    float vr[3], uc[3];
    vr[0] = (float)(i - 1) - cy;  vr[1] = (float)i - cy;  vr[2] = (float)(i + 1) - cy;
    uc[0] = (float)jm - cx;       uc[1] = (float)j - cx;  uc[2] = (float)jp - cx;

    float X[3][3], Y[3][3];
    #pragma unroll
    for (int di = 0; di < 3; ++di) {
        #pragma unroll
        for (int dj = 0; dj < 3; ++dj) {
            const float zz = z[di][dj];
            Y[di][dj] = (zz * vr[di]) * rfx;
            X[di][dj] = (zz * uc[dj]) * rfx;
        }
    }
    // Pad columns/rows give +-0 here; Xc - (+-0) == Xc exactly, matching the
    // conv's zero-pad contribution. No explicit re-zeroing needed.

    // Central-difference D taps (IEEE divides: dE-dW cancellation follows).
    const float dW = okW ? 1.0f / z[1][0] : 0.0f;
    const float dE = okE ? 1.0f / z[1][2] : 0.0f;
    const float dN = 1.0f / z[0][1];
    const float dS = okS ? 1.0f / z[2][1] : 0.0f;

    const float gx = dE - dW;
    const float gy = dS - dN;
    const float nx_t = gx * fx;
    const float ny_t = gy * fy;

    const float h2  = nx_t * nx_t + ny_t * ny_t;
    const float hyp = sqrtf(h2);
    const float ih  = 1.0f / hyp;
    const float csn = copysignf(1.0f, nx_t);
    const float c   = fabsf(nx_t) * ih;          // cos(atan(ny/nx)) >= 0
    const float s   = (ny_t * csn) * ih;         // sin(atan(ny/nx))

    const float S2 = 8.7422780e-8f;              // sin(float(3.141592657) - pi)... = -sin(PI_f)
    const float a  = S2 * s - c;                 // cos(atan(r) + PI_f)
    const float b  = -s - S2 * c;                // sin(atan(r) + PI_f)

    const float Xc = X[1][1], Yc = Y[1][1], Zc = z[1][1];

    float Ssum = 0.0f;     // sum_k 1/nrm_k  (all-positive, factors nx,ny sums)
    float snz  = 0.0f;     // sum_k nzn_k    (sign-mixed: keep IEEE per-term)

    const int off_di[8] = {0, 0, 0, 1, 1, 2, 2, 2};
    const int off_dj[8] = {0, 1, 2, 0, 2, 0, 1, 2};
    #pragma unroll
    for (int k = 0; k < 8; ++k) {
        const int di = off_di[k], dj = off_dj[k];
        const float Xd = Xc - X[di][dj];
        const float Yd = Yc - Y[di][dj];
        const float Zd = Zc - z[di][dj];
        const float w   = nx_t * Xd + ny_t * Yd;
        const float nzi = w / Zd;                      // 0/0 -> NaN, x/0 -> inf
        const float nrm = sqrtf(h2 + nzi * nzi);
        const float rn  = 1.0f / nrm;                  // NaN iff nrm NaN
        const float nzn = nzi / nrm;                   // inf/inf -> NaN
        Ssum += (rn == rn) ? rn : 0.0f;
        snz  += (nzn == nzn) ? nzn : 0.0f;
    }

    const float sum_nx = nx_t * Ssum;
    const float sum_ny = ny_t * Ssum;

    const float num = sum_nx * a + sum_ny * b;
    const float g   = num / snz;

    const float rt  = sqrtf(1.0f + g * g);
    float st  = -(g / rt);                  // sin(-atan g)
    float nzo = 1.0f / rt;                  // cos(-atan g); NaN iff g NaN
    if (fabsf(g) == __builtin_inff()) {     // mirror sinf/cosf at +-1.5707964f
        st  = -copysignf(1.0f, g);
        nzo = -4.3711388e-8f;
    }

    float nxo = st * a;
    float nyo = st * b;
    if (nzo != nzo) { nxo = 0.0f; nyo = 0.0f; nzo = -1.0f; }
    const float sgn = (nyo > 0.0f) ? -1.0f : 1.0f;

    out[idx]            = nxo * sgn;
    out[HWSZ + idx]     = nyo * sgn;
    out[2 * HWSZ + idx] = nzo * sgn;
}

extern "C" void kernel_launch(void* const* d_in, const int* in_sizes, int n_in,
                              void* d_out, int out_size, void* d_ws, size_t ws_size,
                              hipStream_t stream) {
    const float* depth = (const float*)d_in[0];
    const float* cam   = (const float*)d_in[1];
    float* out = (float*)d_out;
    dim3 grid((WW + 255) / 256, HH);
    sne_kernel<<<grid, dim3(256, 1, 1), 0, stream>>>(depth, cam, out);
}

// Round 3
// 17.266 us; speedup vs baseline: 2.2079x; 1.6677x over previous
//
#include <hip/hip_runtime.h>

// SNE — 3x3 stencil surface normals, 1080x1920 f32.
// Round 3: hardware rcp/sqrt on every sign-safe path.
//
//  - Sign-critical chain (sgn = nyo>0 discontinuity): signs of nx_t, ny_t,
//    snz, w_k, Zd_k. v_rcp_f32 is sign-exact + monotonic, so only the D-tap
//    divides feeding the gx,gy cancellations stay IEEE (knife-edge: zS~zN to
//    1e-7 relative flips b -> flips sgn -> error ~2). Everything downstream
//    is magnitude-only or lands in the benign snz~0 -> |g| huge regime.
//  - All sqrt uses are magnitude-only -> raw v_sqrt_f32.
//  - NaN/inf cases match IEEE: w*rcp(+0)=+-inf (w!=0) / NaN (w=0);
//    inf*rcp(inf)=inf*0=NaN; x-x=+0 always.
//  - |g|>=1e18 guard: -g/sqrt(1+g^2) would give -0 on g^2 overflow; reference
//    sin(-atan g) saturates to -+1.0f, cos to -4.3711388e-8f.

#define HH 1080
#define WW 1920
#define HWSZ (HH * WW)

__device__ __forceinline__ float frcp(float x) { return __builtin_amdgcn_rcpf(x); }
__device__ __forceinline__ float fsqrt(float x) { return __builtin_amdgcn_sqrtf(x); }

__global__ __launch_bounds__(256)
void sne_kernel(const float* __restrict__ depth, const float* __restrict__ cam,
                float* __restrict__ out)
{
#pragma clang fp contract(off)
    const int j = blockIdx.x * 256 + threadIdx.x;
    const int i = blockIdx.y;
    if (j >= WW) return;
    const int idx = i * WW + j;

    const float fx = cam[0];
    const float cx = cam[2];
    const float fy = cam[4];
    const float cy = cam[5];

    if ((float)(i - 1) <= cy) {
        out[idx]            = 0.0f;
        out[HWSZ + idx]     = 0.0f;
        out[2 * HWSZ + idx] = -1.0f;
        return;
    }

    const int  jm = j - 1, jp = j + 1;
    const bool okW = (jm >= 0);
    const bool okE = (jp < WW);
    const bool okS = (i + 1 < HH);

    const float* rowN = depth + (size_t)(i - 1) * WW;
    const float* rowC = depth + (size_t)i * WW;
    const float* rowS = depth + (size_t)(i + 1) * WW;

    float z[3][3];
    z[0][0] = okW ? rowN[jm] : 0.0f;  z[0][1] = rowN[j];  z[0][2] = okE ? rowN[jp] : 0.0f;
    z[1][0] = okW ? rowC[jm] : 0.0f;  z[1][1] = rowC[j];  z[1][2] = okE ? rowC[jp] : 0.0f;
    if (okS) {
        z[2][0] = okW ? rowS[jm] : 0.0f;  z[2][1] = rowS[j];  z[2][2] = okE ? rowS[jp] : 0.0f;
    } else {
        z[2][0] = 0.0f;  z[2][1] = 0.0f;  z[2][2] = 0.0f;
    }

    const float rfx = frcp(fx);

    float vr[3], uc[3];
    vr[0] = (float)(i - 1) - cy;  vr[1] = (float)i - cy;  vr[2] = (float)(i + 1) - cy;
    uc[0] = (float)jm - cx;       uc[1] = (float)j - cx;  uc[2] = (float)jp - cx;

    float X[3][3], Y[3][3];
    #pragma unroll
    for (int di = 0; di < 3; ++di) {
        #pragma unroll
        for (int dj = 0; dj < 3; ++dj) {
            const float zz = z[di][dj];
            Y[di][dj] = (zz * vr[di]) * rfx;
            X[di][dj] = (zz * uc[dj]) * rfx;
        }
    }

    // D taps: IEEE divides (sign-critical gx,gy cancellations follow).
    const float dW = okW ? 1.0f / z[1][0] : 0.0f;
    const float dE = okE ? 1.0f / z[1][2] : 0.0f;
    const float dN = 1.0f / z[0][1];
    const float dS = okS ? 1.0f / z[2][1] : 0.0f;

    const float gx = dE - dW;
    const float gy = dS - dN;
    const float nx_t = gx * fx;
    const float ny_t = gy * fy;

    const float h2  = nx_t * nx_t + ny_t * ny_t;
    const float ih  = frcp(fsqrt(h2));           // magnitudes only
    const float csn = copysignf(1.0f, nx_t);
    const float c   = fabsf(nx_t) * ih;          // cos(atan(ny/nx)) >= 0
    const float s   = (ny_t * csn) * ih;         // sin(atan(ny/nx))

    const float S2 = 8.7422780e-8f;              // -sin(PI_f), cos(PI_f) = -1 exactly
    const float a  = S2 * s - c;                 // cos(atan(r) + PI_f)
    const float b  = -s - S2 * c;                // sin(atan(r) + PI_f)

    const float Xc = X[1][1], Yc = Y[1][1], Zc = z[1][1];

    float Ssum = 0.0f;     // sum_k 1/nrm_k  (all-positive)
    float snz  = 0.0f;     // sum_k nzn_k    (sign-mixed; signs exact under rcp)

    const int off_di[8] = {0, 0, 0, 1, 1, 2, 2, 2};
    const int off_dj[8] = {0, 1, 2, 0, 2, 0, 1, 2};
    #pragma unroll
    for (int k = 0; k < 8; ++k) {
        const int di = off_di[k], dj = off_dj[k];
        const float Xd = Xc - X[di][dj];
        const float Yd = Yc - Y[di][dj];
        const float Zd = Zc - z[di][dj];
        const float w   = nx_t * Xd + ny_t * Yd;
        const float nzi = w * frcp(Zd);                // +0 -> +inf; 0*inf -> NaN
        const float nrm = fsqrt(h2 + nzi * nzi);
        const float rn  = frcp(nrm);                   // inf -> 0; NaN -> NaN
        const float nzn = nzi * rn;                    // inf*0 -> NaN (= inf/inf)
        Ssum += (rn == rn) ? rn : 0.0f;
        snz  += (nzn == nzn) ? nzn : 0.0f;
    }

    const float sum_nx = nx_t * Ssum;
    const float sum_ny = ny_t * Ssum;

    const float num = sum_nx * a + sum_ny * b;
    const float g   = num * frcp(snz);           // sign exact; +-inf/NaN propagate

    const float rt  = fsqrt(1.0f + g * g);
    const float irt = frcp(rt);
    float st  = -(g * irt);                      // sin(-atan g)
    float nzo = irt;                             // cos(-atan g); NaN iff g NaN
    if (fabsf(g) >= 1e18f) {                     // saturation incl. g^2 overflow & inf
        st  = -copysignf(1.0f, g);
        nzo = -4.3711388e-8f;                    // cosf(1.5707964f)
    }

    float nxo = st * a;
    float nyo = st * b;
    if (nzo != nzo) { nxo = 0.0f; nyo = 0.0f; nzo = -1.0f; }
    const float sgn = (nyo > 0.0f) ? -1.0f : 1.0f;

    out[idx]            = nxo * sgn;
    out[HWSZ + idx]     = nyo * sgn;
    out[2 * HWSZ + idx] = nzo * sgn;
}

extern "C" void kernel_launch(void* const* d_in, const int* in_sizes, int n_in,
                              void* d_out, int out_size, void* d_ws, size_t ws_size,
                              hipStream_t stream) {
    const float* depth = (const float*)d_in[0];
    const float* cam   = (const float*)d_in[1];
    float* out = (float*)d_out;
    dim3 grid((WW + 255) / 256, HH);
    sne_kernel<<<grid, dim3(256, 1, 1), 0, stream>>>(depth, cam, out);
}

// Round 4
// 15.559 us; speedup vs baseline: 2.4501x; 1.1097x over previous
//
#include <hip/hip_runtime.h>

// SNE — 3x3 stencil surface normals, 1080x1920 f32.
// Round 4: full hw-rcp/rsq + algebraic loop collapse.
//
// Continuity analysis (why ulp-level sign flips are safe):
//  - nx_t sign flip: csn flips s -> flips b and st; nxo=st*a, nyo=st*b are
//    quadratic in csn -> invariant. Output continuous across nx=0.
//  - snz sign flip: st flips sign, but sgn=(nyo>0) flips with it -> out_x,
//    out_y invariant, out_z changes by 2*nzo -> 0. Continuous across snz=0.
//  - w_k sign flip near 0: contribution -> 0 continuously.
//  Only b==0 is a true discontinuity (measure ~1e-14/px, same in all rounds).
//
// k-loop algebra: w_k = nx*(Xc-Xk)+ny*(Yc-Yk) = cp - z_k*q_k with
//   q_k = au[col]+bv[row], au = (nx/fx)*(u-cx), bv = (ny/fx)*(v-cy),
//   cp = Zc*(au[1]+bv[1]).
// nzn_k = nzi/nrm = w*copysign(rsq(Zd^2*h2 + w^2), Zd); rn_k = |Zd|*rsq(t).
// Gate (Zd != 0) reproduces reference inf/NaN exclusion exactly:
//   Zd=0,w!=0: ref nzi=inf -> rn=0 (adds 0), nzn=NaN (excluded) == skip both.
//   Zd=0,w=0:  ref all NaN (excluded)                           == skip both.
//   h2=0: a,b NaN -> num NaN -> g NaN -> bad branch, both ways.

#define HH 1080
#define WW 1920
#define HWSZ (HH * WW)

__device__ __forceinline__ float frcp(float x)  { return __builtin_amdgcn_rcpf(x); }
__device__ __forceinline__ float frsq(float x)  { return __builtin_amdgcn_rsqf(x); }

__global__ __launch_bounds__(256)
void sne_kernel(const float* __restrict__ depth, const float* __restrict__ cam,
                float* __restrict__ out)
{
    const int j = blockIdx.x * 256 + threadIdx.x;
    const int i = blockIdx.y;
    if (j >= WW) return;
    const int idx = i * WW + j;

    const float fx = cam[0];
    const float cx = cam[2];
    const float fy = cam[4];
    const float cy = cam[5];

    // Rows whose 3x3 window touches a Z=0 (D=inf) row: deterministic (0,0,-1).
    if ((float)(i - 1) <= cy) {
        out[idx]            = 0.0f;
        out[HWSZ + idx]     = 0.0f;
        out[2 * HWSZ + idx] = -1.0f;
        return;
    }

    const int  jm = j - 1, jp = j + 1;
    const bool okW = (jm >= 0);
    const bool okE = (jp < WW);
    const bool okS = (i + 1 < HH);

    const float* rowN = depth + (size_t)(i - 1) * WW;
    const float* rowC = depth + (size_t)i * WW;
    const float* rowS = depth + (size_t)(i + 1) * WW;

    float z[3][3];
    z[0][0] = okW ? rowN[jm] : 0.0f;          z[0][1] = rowN[j];
    z[0][2] = okE ? rowN[jp] : 0.0f;
    z[1][0] = okW ? rowC[jm] : 0.0f;          z[1][1] = rowC[j];
    z[1][2] = okE ? rowC[jp] : 0.0f;
    z[2][0] = (okS && okW) ? rowS[jm] : 0.0f; z[2][1] = okS ? rowS[j] : 0.0f;
    z[2][2] = (okS && okE) ? rowS[jp] : 0.0f;

    // Central-difference D taps via hw rcp (sign flips proven benign).
    const float dW = okW ? frcp(z[1][0]) : 0.0f;
    const float dE = okE ? frcp(z[1][2]) : 0.0f;
    const float dN = frcp(z[0][1]);
    const float dS = okS ? frcp(z[2][1]) : 0.0f;

    const float gx = dE - dW;
    const float gy = dS - dN;
    const float nx_t = gx * fx;
    const float ny_t = gy * fy;

    const float h2  = nx_t * nx_t + ny_t * ny_t;
    const float ih  = frsq(h2);                 // h2=0 -> inf -> c,s NaN (wanted)
    const float csn = copysignf(1.0f, nx_t);
    const float c   = fabsf(nx_t) * ih;         // cos(atan(ny/nx)) >= 0
    const float s   = (ny_t * csn) * ih;        // sin(atan(ny/nx))

    const float S2 = 8.7422780e-8f;             // PI_f = pi + S2; cos(PI_f)=-1 in f32
    const float a  = S2 * s - c;                // cos(atan(r) + PI_f)
    const float b  = -s - S2 * c;               // sin(atan(r) + PI_f)

    // Folded w-coefficients.
    const float rfx = frcp(fx);
    const float nxr = nx_t * rfx;
    const float nyr = ny_t * rfx;
    float au[3], bv[3];
    au[0] = nxr * ((float)jm - cx);
    au[1] = nxr * ((float)j  - cx);
    au[2] = nxr * ((float)jp - cx);
    bv[0] = nyr * ((float)(i - 1) - cy);
    bv[1] = nyr * ((float)i       - cy);
    bv[2] = nyr * ((float)(i + 1) - cy);
    const float Zc = z[1][1];
    const float cp = Zc * (au[1] + bv[1]);

    float Ssum = 0.0f;     // sum_k 1/nrm_k  (nonnegative terms)
    float snz  = 0.0f;     // sum_k nzn_k

    const int off_di[8] = {0, 0, 0, 1, 1, 2, 2, 2};
    const int off_dj[8] = {0, 1, 2, 0, 2, 0, 1, 2};
    #pragma unroll
    for (int k = 0; k < 8; ++k) {
        const float zk = z[off_di[k]][off_dj[k]];
        const float q  = au[off_dj[k]] + bv[off_di[k]];
        const float w  = cp - zk * q;                 // fma
        const float Zd = Zc - zk;
        const float t  = (Zd * Zd) * h2 + w * w;      // fma-chain
        const float r  = frsq(t);
        const float nzn = w * copysignf(r, Zd);
        const float rn  = fabsf(Zd) * r;
        const bool  ok  = (Zd != 0.0f);
        Ssum += ok ? rn  : 0.0f;
        snz  += ok ? nzn : 0.0f;
    }

    const float sum_nx = nx_t * Ssum;
    const float sum_ny = ny_t * Ssum;
    const float num    = sum_nx * a + sum_ny * b;
    const float g      = num * frcp(snz);        // +-0 -> +-inf; 0*inf -> NaN

    const float t2  = 1.0f + g * g;
    const float irt = frsq(t2);
    float st  = -(g * irt);                      // sin(-atan g)
    float nzo = irt;                             // cos(-atan g); NaN iff g NaN
    if (fabsf(g) >= 1e18f) {                     // saturation (incl. g^2 ovf, inf)
        st  = -copysignf(1.0f, g);
        nzo = -4.3711388e-8f;                    // cosf(1.5707964f)
    }

    float nxo = st * a;
    float nyo = st * b;
    if (nzo != nzo) { nxo = 0.0f; nyo = 0.0f; nzo = -1.0f; }
    const float sgn = (nyo > 0.0f) ? -1.0f : 1.0f;

    out[idx]            = nxo * sgn;
    out[HWSZ + idx]     = nyo * sgn;
    out[2 * HWSZ + idx] = nzo * sgn;
}

extern "C" void kernel_launch(void* const* d_in, const int* in_sizes, int n_in,
                              void* d_out, int out_size, void* d_ws, size_t ws_size,
                              hipStream_t stream) {
    const float* depth = (const float*)d_in[0];
    const float* cam   = (const float*)d_in[1];
    float* out = (float*)d_out;
    dim3 grid((WW + 255) / 256, HH);
    sne_kernel<<<grid, dim3(256, 1, 1), 0, stream>>>(depth, cam, out);
}